// Round 1
// baseline (1729.379 us; speedup 1.0000x reference)
//
#include <hip/hip_runtime.h>

#define FS 11
#define HFS 5

constexpr int Bn = 8, Cn = 19, Hn = 512, Wn = 512;
constexpr int HWn = Hn * Wn;                      // 262144 = 2^18
constexpr long long CHWn = (long long)Cn * HWn;   // 4980736
constexpr long long TOTn = (long long)Bn * CHWn;  // 39845888

// taps[b][dim][j]: dim0 = kh (H-direction), dim1 = kw (W-direction, scaled by weight)
__global__ void k_taps(const float* __restrict__ spacing,
                       const float* __restrict__ inv_theta,
                       const float* __restrict__ wgt,
                       float* __restrict__ taps) {
    int t = threadIdx.x;
    if (t < Bn * 2 * FS) {
        int j = t % FS;
        int dim = (t / FS) & 1;
        int b = t / (2 * FS);
        float d = spacing[b * 2 + dim] * (float)(j - HFS);
        float a = d * inv_theta[dim];
        float k = __expf(-0.5f * a * a);
        if (j == HFS) k = 0.0f;          // message passing excludes self
        if (dim == 1) k *= wgt[0];       // fold smoothness_weight into kw
        taps[t] = k;
    }
}

// softmax over C=19 at each pixel; 4 pixels (consecutive w) per thread
__global__ __launch_bounds__(256) void k_softmax(const float* __restrict__ x,
                                                 float* __restrict__ q) {
    int tid = blockIdx.x * 256 + threadIdx.x;
    int p4 = tid * 4;                    // pixel*1 index within B*H*W, aligned 4
    int b = p4 >> 18;                    // / HW
    int r = p4 & (HWn - 1);
    const float* xp = x + (long long)b * CHWn + r;
    float* qp = q + (long long)b * CHWn + r;

    float4 v[Cn];
#pragma unroll
    for (int c = 0; c < Cn; c++)
        v[c] = *(const float4*)(xp + (long long)c * HWn);

    float4 m = v[0];
#pragma unroll
    for (int c = 1; c < Cn; c++) {
        m.x = fmaxf(m.x, v[c].x);
        m.y = fmaxf(m.y, v[c].y);
        m.z = fmaxf(m.z, v[c].z);
        m.w = fmaxf(m.w, v[c].w);
    }
    float4 s = {0.f, 0.f, 0.f, 0.f};
#pragma unroll
    for (int c = 0; c < Cn; c++) {
        v[c].x = __expf(v[c].x - m.x);
        v[c].y = __expf(v[c].y - m.y);
        v[c].z = __expf(v[c].z - m.z);
        v[c].w = __expf(v[c].w - m.w);
        s.x += v[c].x; s.y += v[c].y; s.z += v[c].z; s.w += v[c].w;
    }
    float4 rin = {1.0f / s.x, 1.0f / s.y, 1.0f / s.z, 1.0f / s.w};
#pragma unroll
    for (int c = 0; c < Cn; c++) {
        float4 o = {v[c].x * rin.x, v[c].y * rin.y, v[c].z * rin.z, v[c].w * rin.w};
        *(float4*)(qp + (long long)c * HWn) = o;
    }
}

// conv along H (zero pad, center tap skipped); 4 consecutive w per thread
__global__ __launch_bounds__(256) void k_convh(const float* __restrict__ q,
                                               float* __restrict__ t,
                                               const float* __restrict__ taps) {
    int tid = blockIdx.x * 256 + threadIdx.x;
    long long i4 = (long long)tid * 4;
    int w = (int)(i4 & (Wn - 1));
    int h = (int)((i4 >> 9) & (Hn - 1));
    int cb = (int)(i4 >> 18);            // b*C + c (uniform per block)
    int b = cb / Cn;
    const float* kh = taps + b * (2 * FS);
    const float* qcol = q + (long long)cb * HWn + w;

    float4 acc = {0.f, 0.f, 0.f, 0.f};
#pragma unroll
    for (int j = 0; j < FS; j++) {
        if (j == HFS) continue;          // center tap is zero
        int hh = h + j - HFS;
        if (hh < 0 || hh >= Hn) continue;
        float k = kh[j];
        float4 val = *(const float4*)(qcol + (long long)hh * Wn);
        acc.x = fmaf(k, val.x, acc.x);
        acc.y = fmaf(k, val.y, acc.y);
        acc.z = fmaf(k, val.z, acc.z);
        acc.w = fmaf(k, val.w, acc.w);
    }
    *(float4*)(t + i4) = acc;
}

// conv along W (zero pad, center tap skipped) + x = x0 + result; 4 outputs/thread
__global__ __launch_bounds__(256) void k_convw(const float* __restrict__ t,
                                               const float* __restrict__ x0,
                                               float* __restrict__ out,
                                               const float* __restrict__ taps) {
    int tid = blockIdx.x * 256 + threadIdx.x;
    long long i4 = (long long)tid * 4;
    int w = (int)(i4 & (Wn - 1));
    int cb = (int)(i4 >> 18);
    int b = cb / Cn;
    const float* kw = taps + b * (2 * FS) + FS;   // weight-scaled
    const float* row = t + (i4 - w);              // row start

    float arr[20];
#pragma unroll
    for (int g = 0; g < 5; g++) {
        int ws = w - 8 + 4 * g;
        float4 vv = {0.f, 0.f, 0.f, 0.f};
        if (ws >= 0 && ws < Wn) vv = *(const float4*)(row + ws);
        arr[4 * g + 0] = vv.x; arr[4 * g + 1] = vv.y;
        arr[4 * g + 2] = vv.z; arr[4 * g + 3] = vv.w;
    }
    float o0 = 0.f, o1 = 0.f, o2 = 0.f, o3 = 0.f;
#pragma unroll
    for (int j = 0; j < FS; j++) {
        if (j == HFS) continue;
        float k = kw[j];
        o0 = fmaf(k, arr[0 + j + 3], o0);
        o1 = fmaf(k, arr[1 + j + 3], o1);
        o2 = fmaf(k, arr[2 + j + 3], o2);
        o3 = fmaf(k, arr[3 + j + 3], o3);
    }
    float4 xv = *(const float4*)(x0 + i4);
    float4 res = {xv.x + o0, xv.y + o1, xv.z + o2, xv.w + o3};
    *(float4*)(out + i4) = res;
}

extern "C" void kernel_launch(void* const* d_in, const int* in_sizes, int n_in,
                              void* d_out, int out_size, void* d_ws, size_t ws_size,
                              hipStream_t stream) {
    const float* x0      = (const float*)d_in[0];
    const float* spacing = (const float*)d_in[1];
    const float* wgt     = (const float*)d_in[2];
    const float* itheta  = (const float*)d_in[3];
    float* out = (float*)d_out;

    float* qbuf = (float*)d_ws;
    float* tbuf = qbuf + TOTn;
    float* taps = tbuf + TOTn;

    k_taps<<<1, 256, 0, stream>>>(spacing, itheta, wgt, taps);

    const int gpix = (Bn * HWn / 4) / 256;        // 2048 blocks
    const int gel = (int)(TOTn / 4 / 256);        // 38912 blocks

    for (int it = 0; it < 5; it++) {
        const float* xin = (it == 0) ? x0 : (const float*)out;
        k_softmax<<<gpix, 256, 0, stream>>>(xin, qbuf);
        k_convh<<<gel, 256, 0, stream>>>(qbuf, tbuf, taps);
        k_convw<<<gel, 256, 0, stream>>>(tbuf, x0, out, taps);
    }
}

// Round 2
// 1070.541 us; speedup vs baseline: 1.6154x; 1.6154x over previous
//
#include <hip/hip_runtime.h>

#define FS 11
#define HFS 5

constexpr int Bn = 8, Cn = 19, Hn = 512, Wn = 512;
constexpr int HWn = Hn * Wn;                      // 262144 = 2^18
constexpr long long CHWn = (long long)Cn * HWn;   // 4980736
constexpr long long TOTn = (long long)Bn * CHWn;  // 39845888

// fused conv tile params
constexpr int TH = 64, TW = 64;
constexpr int QROWS = TH + 10;   // 74 rows: h0-5 .. h0+68
constexpr int QSTR  = 80;        // cols w0-8 .. w0+71 (float4-aligned halo)

// taps[b][dim][j]: dim0 = kh (H-direction), dim1 = kw (W-direction, scaled by weight)
__global__ void k_taps(const float* __restrict__ spacing,
                       const float* __restrict__ inv_theta,
                       const float* __restrict__ wgt,
                       float* __restrict__ taps) {
    int t = threadIdx.x;
    if (t < Bn * 2 * FS) {
        int j = t % FS;
        int dim = (t / FS) & 1;
        int b = t / (2 * FS);
        float d = spacing[b * 2 + dim] * (float)(j - HFS);
        float a = d * inv_theta[dim];
        float k = __expf(-0.5f * a * a);
        if (j == HFS) k = 0.0f;          // message passing excludes self
        if (dim == 1) k *= wgt[0];       // fold smoothness_weight into kw
        taps[t] = k;
    }
}

// softmax over C=19 at each pixel; 4 pixels (consecutive w) per thread
__global__ __launch_bounds__(256) void k_softmax(const float* __restrict__ x,
                                                 float* __restrict__ q) {
    int tid = blockIdx.x * 256 + threadIdx.x;
    int p4 = tid * 4;                    // pixel index within B*H*W, aligned 4
    int b = p4 >> 18;                    // / HW
    int r = p4 & (HWn - 1);
    const float* xp = x + (long long)b * CHWn + r;
    float* qp = q + (long long)b * CHWn + r;

    float4 v[Cn];
#pragma unroll
    for (int c = 0; c < Cn; c++)
        v[c] = *(const float4*)(xp + (long long)c * HWn);

    float4 m = v[0];
#pragma unroll
    for (int c = 1; c < Cn; c++) {
        m.x = fmaxf(m.x, v[c].x);
        m.y = fmaxf(m.y, v[c].y);
        m.z = fmaxf(m.z, v[c].z);
        m.w = fmaxf(m.w, v[c].w);
    }
    float4 s = {0.f, 0.f, 0.f, 0.f};
#pragma unroll
    for (int c = 0; c < Cn; c++) {
        v[c].x = __expf(v[c].x - m.x);
        v[c].y = __expf(v[c].y - m.y);
        v[c].z = __expf(v[c].z - m.z);
        v[c].w = __expf(v[c].w - m.w);
        s.x += v[c].x; s.y += v[c].y; s.z += v[c].z; s.w += v[c].w;
    }
    float4 rin = {1.0f / s.x, 1.0f / s.y, 1.0f / s.z, 1.0f / s.w};
#pragma unroll
    for (int c = 0; c < Cn; c++) {
        float4 o = {v[c].x * rin.x, v[c].y * rin.y, v[c].z * rin.z, v[c].w * rin.w};
        *(float4*)(qp + (long long)c * HWn) = o;
    }
}

// Fused convH + convW + (x = x0 + m) for one (b,c) 64x64 tile.
// qs: 74x80 halo tile of q; ts: 64x80 intermediate (never hits HBM).
__global__ __launch_bounds__(256) void k_conv(const float* __restrict__ q,
                                              const float* __restrict__ x0,
                                              float* __restrict__ out,
                                              const float* __restrict__ taps) {
    __shared__ float qs[QROWS * QSTR];   // 23680 B
    __shared__ float ts[TH * QSTR];      // 20480 B

    const int w0 = blockIdx.x * TW;
    const int h0 = blockIdx.y * TH;
    const int bc = blockIdx.z;           // b*Cn + c
    const int b  = bc / Cn;
    const int tid = threadIdx.x;

    const float* tp = taps + b * (2 * FS);
    float kh[FS], kw[FS];
#pragma unroll
    for (int j = 0; j < FS; j++) { kh[j] = tp[j]; kw[j] = tp[FS + j]; }

    const float* qc = q + (long long)bc * HWn;

    // ---- load q ext tile: rows h0-5..h0+68, cols w0-8..w0+71 (zeros OOB) ----
    for (int i = tid; i < QROWS * 20; i += 256) {
        int r  = i / 20, c4 = i % 20;
        int hh = h0 - 5 + r;
        int g  = w0 - 8 + 4 * c4;        // float4 is fully in or fully out (g%4==0)
        float4 v = {0.f, 0.f, 0.f, 0.f};
        if (hh >= 0 && hh < Hn && g >= 0 && g <= Wn - 4)
            v = *(const float4*)(qc + (long long)hh * Wn + g);
        *(float4*)(&qs[r * QSTR + 4 * c4]) = v;
    }
    __syncthreads();

    // ---- convH: t rows 0..63 (= global h0..h0+63), all 80 cols ----
    // task: col c (0..79) x h-strip s (0..3, 16 rows each); 320 tasks
    for (int task = tid; task < 80 * 4; task += 256) {
        int c = task % 80;
        int s = task / 80;
        int rbase = s * 16;
        float qv[26];
#pragma unroll
        for (int k = 0; k < 26; k++) qv[k] = qs[(rbase + k) * QSTR + c];
#pragma unroll
        for (int k = 0; k < 16; k++) {
            float a = 0.f;
#pragma unroll
            for (int j = 0; j < FS; j++) {
                if (j == HFS) continue;  // center tap zero
                a = fmaf(kh[j], qv[k + j], a);
            }
            ts[(rbase + k) * QSTR + c] = a;
        }
    }
    __syncthreads();

    // ---- convW + epilogue: task: row h (0..63) x w-strip s (0..7, 8 cols) ----
    for (int task = tid; task < 512; task += 256) {
        int h  = task >> 3;
        int s  = task & 7;
        int cb = s * 8;                  // tile-local out cols cb..cb+7
        float tv[24];                    // ts cols cb..cb+23 (need cb+3..cb+20)
#pragma unroll
        for (int g4 = 0; g4 < 6; g4++) {
            float4 v = *(const float4*)(&ts[h * QSTR + cb + 4 * g4]);
            tv[4 * g4 + 0] = v.x; tv[4 * g4 + 1] = v.y;
            tv[4 * g4 + 2] = v.z; tv[4 * g4 + 3] = v.w;
        }
        float o[8];
#pragma unroll
        for (int k = 0; k < 8; k++) {
            float a = 0.f;
#pragma unroll
            for (int j = 0; j < FS; j++) {
                if (j == HFS) continue;
                a = fmaf(kw[j], tv[k + 3 + j], a);
            }
            o[k] = a;
        }
        long long gidx = (long long)bc * HWn + (long long)(h0 + h) * Wn + (w0 + cb);
        float4 xa = *(const float4*)(x0 + gidx);
        float4 xb = *(const float4*)(x0 + gidx + 4);
        float4 ra = {xa.x + o[0], xa.y + o[1], xa.z + o[2], xa.w + o[3]};
        float4 rb = {xb.x + o[4], xb.y + o[5], xb.z + o[6], xb.w + o[7]};
        *(float4*)(out + gidx)     = ra;
        *(float4*)(out + gidx + 4) = rb;
    }
}

extern "C" void kernel_launch(void* const* d_in, const int* in_sizes, int n_in,
                              void* d_out, int out_size, void* d_ws, size_t ws_size,
                              hipStream_t stream) {
    const float* x0      = (const float*)d_in[0];
    const float* spacing = (const float*)d_in[1];
    const float* wgt     = (const float*)d_in[2];
    const float* itheta  = (const float*)d_in[3];
    float* out = (float*)d_out;

    float* qbuf = (float*)d_ws;
    float* taps = qbuf + TOTn;

    k_taps<<<1, 256, 0, stream>>>(spacing, itheta, wgt, taps);

    const int gpix = (Bn * HWn / 4) / 256;        // 2048 blocks
    dim3 gconv(Wn / TW, Hn / TH, Bn * Cn);        // 8 x 8 x 152 = 9728 blocks

    for (int it = 0; it < 5; it++) {
        const float* xin = (it == 0) ? x0 : (const float*)out;
        k_softmax<<<gpix, 256, 0, stream>>>(xin, qbuf);
        k_conv<<<gconv, 256, 0, stream>>>(qbuf, x0, out, taps);
    }
}